// Round 19
// baseline (294.137 us; speedup 1.0000x reference)
//
#include <hip/hip_runtime.h>
#include <math.h>

#define B_ 16
#define S_ 512
#define DM 1024
#define NH 16
#define DFF 2048

typedef short bf16x8 __attribute__((ext_vector_type(8)));
typedef float f32x4 __attribute__((ext_vector_type(4)));
typedef unsigned short u16;

__device__ __forceinline__ u16 f2bf(float f) {
  unsigned int u = __float_as_uint(f);
  u += 0x7FFF + ((u >> 16) & 1);
  return (u16)(u >> 16);
}

__device__ __forceinline__ float bf2f(u16 u) {
  return __uint_as_float(((unsigned)u) << 16);
}

__device__ __forceinline__ unsigned cvtpk_bf16(float lo, float hi) {
  unsigned r;
  asm("v_cvt_pk_bf16_f32 %0, %1, %2" : "=v"(r) : "v"(lo), "v"(hi));
  return r;
}

__device__ __forceinline__ float gelu_exact(float x) {
  return 0.5f * x * (1.0f + erff(x * 0.70710678118654752f));
}

__device__ __forceinline__ void gload_lds16(const void* g, void* l) {
  __builtin_amdgcn_global_load_lds((const __attribute__((address_space(1))) void*)g,
                                   (__attribute__((address_space(3))) void*)l, 16, 0, 0);
}

// log2(e)/8: folded into Q at the QKV epilogue so softmax runs in exp2 domain.
#define QSCALE 0.18033688011112042f
#define MASKNEG -1.442695e10f

// ---------------------------------------------------------------- fused preprocessing
__global__ __launch_bounds__(256)
void prep_all(const float* __restrict__ Wq, const float* __restrict__ Wk,
              const float* __restrict__ Wv, const float* __restrict__ Wo,
              const float* __restrict__ W1, const float* __restrict__ W2,
              u16* __restrict__ wqkvt, u16* __restrict__ wot,
              u16* __restrict__ w1t, u16* __restrict__ w2t,
              const float* __restrict__ bq, const float* __restrict__ bk,
              const float* __restrict__ bv, float* __restrict__ bqkv,
              const float* __restrict__ x, u16* __restrict__ xb) {
  const int bid = blockIdx.x;
  if (bid >= 8204) {  // x -> bf16
    int i = ((bid - 8204) * 256 + threadIdx.x) * 4;
    float4 v = *(const float4*)(x + i);
    uint2 pk;
    pk.x = (unsigned)f2bf(v.x) | ((unsigned)f2bf(v.y) << 16);
    pk.y = (unsigned)f2bf(v.z) | ((unsigned)f2bf(v.w) << 16);
    *(uint2*)(xb + i) = pk;
    return;
  }
  if (bid >= 8192) {  // bias concat
    int i = (bid - 8192) * 256 + threadIdx.x;
    bqkv[i] = (i < 1024) ? bq[i] : ((i < 2048) ? bk[i - 1024] : bv[i - 2048]);
    return;
  }
  const float* W;
  u16* Wt;
  int K, N, bx, by;
  if (bid < 4096) {
    const int m = bid >> 10, t = bid & 1023;
    K = 1024; N = 1024; bx = t & 31; by = t >> 5;
    W = (m == 0) ? Wq : (m == 1) ? Wk : (m == 2) ? Wv : Wo;
    Wt = (m == 3) ? wot : wqkvt + m * 1048576;
  } else if (bid < 6144) {
    const int t = bid - 4096;
    K = 1024; N = 2048; bx = t & 63; by = t >> 6; W = W1; Wt = w1t;
  } else {
    const int t = bid - 6144;
    K = 2048; N = 1024; bx = t & 31; by = t >> 5; W = W2; Wt = w2t;
  }
  __shared__ float tile[32][33];
  const int n0 = bx * 32, k0 = by * 32;
  const int tx = threadIdx.x & 31, ty = threadIdx.x >> 5;
#pragma unroll
  for (int j = 0; j < 32; j += 8)
    tile[ty + j][tx] = W[(size_t)(k0 + ty + j) * N + n0 + tx];
  __syncthreads();
#pragma unroll
  for (int j = 0; j < 32; j += 8)
    Wt[(size_t)(n0 + ty + j) * K + k0 + tx] = f2bf(tile[tx][ty + j]);
}

// ---------------------------------------------------------------- GEMM 256x128, BK=32, ring-3, 8-wave
// (R18, verified) one-barrier ring-3; per K-tile {8 ds_read_b128; 3 gload_lds;
// setprio+16 MFMA; vmcnt(3)+lgkmcnt(0); s_barrier}.
// EPI: 1 = GELU -> bf16; 2 = fp32; 3 = QKV split (Q pre-scale + vT 8B-packed); 4 = bf16.
template <int EPI>
__global__ __launch_bounds__(512, 4)
void gemm_mfma(const u16* __restrict__ A, const u16* __restrict__ Bt,
               const float* __restrict__ bias, void* __restrict__ Cout,
               u16* __restrict__ vT, int M, int N, int K) {
  __shared__ __align__(16) char lds[73728];
  const int tid = threadIdx.x;
  const int w = tid >> 6, lane = tid & 63;
  const int wm = w >> 1, wn = w & 1;

  const int gx = gridDim.x;
  const int nwg = gx * gridDim.y;
  const int lin = blockIdx.y * gx + blockIdx.x;
  const int wg = (lin & 7) * (nwg >> 3) + (lin >> 3);
  const int bm = wg / gx, bn = wg % gx;

  const int NT = K >> 5;

  const int srow = tid >> 2;
  const int skel = ((lane & 3) ^ ((lane >> 4) & 3)) * 8;
  const u16* gA = A + (size_t)(bm * 256 + srow) * K + skel;
  const u16* gB = Bt + (size_t)(bn * 128 + srow) * K + skel;
  const size_t rs128 = (size_t)128 * K;
  const int dstb = w * 1024;

  const int lr = lane & 15, kg = lane >> 4;
  const int kslot = (kg ^ ((lr >> 2) & 3)) << 4;
  const int fAoff = (wm * 64 + lr) * 64 + kslot;
  const int fBoff = 16384 + (wn * 64 + lr) * 64 + kslot;

  f32x4 acc[4][4];
#pragma unroll
  for (int i = 0; i < 4; ++i)
#pragma unroll
    for (int j = 0; j < 4; ++j) acc[i][j] = (f32x4){0.f, 0.f, 0.f, 0.f};

#define STAGE_T(t_, sl_)                                         \
  do {                                                           \
    const u16* ga_ = gA + (size_t)(t_) * 32;                     \
    const u16* gb_ = gB + (size_t)(t_) * 32;                     \
    char* d_ = lds + (sl_) * 24576 + dstb;                       \
    gload_lds16(ga_, d_);                                        \
    gload_lds16(ga_ + rs128, d_ + 8192);                         \
    gload_lds16(gb_, d_ + 16384);                                \
  } while (0)

  STAGE_T(0, 0);
  STAGE_T(1, 1);
  asm volatile("s_waitcnt vmcnt(3)" ::: "memory");
  __builtin_amdgcn_s_barrier();
  __builtin_amdgcn_sched_barrier(0);

  int cs = 0, ss = 2;
  for (int t = 0; t < NT; ++t) {
    const int st = (t + 2 < NT) ? (t + 2) : (NT - 1);
    const char* fA = lds + cs * 24576 + fAoff;
    const char* fB = lds + cs * 24576 + fBoff;
    bf16x8 av[4], bv[4];
#pragma unroll
    for (int mi = 0; mi < 4; ++mi) av[mi] = *(const bf16x8*)(fA + mi * 1024);
#pragma unroll
    for (int ni = 0; ni < 4; ++ni) bv[ni] = *(const bf16x8*)(fB + ni * 1024);
    STAGE_T(st, ss);
    __builtin_amdgcn_s_setprio(1);
#pragma unroll
    for (int mi = 0; mi < 4; ++mi)
#pragma unroll
      for (int ni = 0; ni < 4; ++ni)
        acc[mi][ni] = __builtin_amdgcn_mfma_f32_16x16x32_bf16(av[mi], bv[ni], acc[mi][ni], 0, 0, 0);
    __builtin_amdgcn_s_setprio(0);
    asm volatile("s_waitcnt vmcnt(3) lgkmcnt(0)" ::: "memory");
    __builtin_amdgcn_s_barrier();
    __builtin_amdgcn_sched_barrier(0);
    cs = (cs == 2) ? 0 : cs + 1;
    ss = (ss == 2) ? 0 : ss + 1;
  }
#undef STAGE_T

  const int crow0 = bm * 256 + wm * 64;
  const int ccol0 = bn * 128 + wn * 64;
#pragma unroll
  for (int mi = 0; mi < 4; ++mi) {
#pragma unroll
    for (int ni = 0; ni < 4; ++ni) {
      const int col = ccol0 + ni * 16 + lr;
      const float bv_ = bias[col];
      const int rowb = crow0 + mi * 16 + (lane >> 4) * 4;
      float v[4];
#pragma unroll
      for (int r = 0; r < 4; ++r) v[r] = acc[mi][ni][r] + bv_;
      if (EPI == 1) {
#pragma unroll
        for (int r = 0; r < 4; ++r)
          ((u16*)Cout)[(size_t)(rowb + r) * N + col] = f2bf(gelu_exact(v[r]));
      } else if (EPI == 2) {
#pragma unroll
        for (int r = 0; r < 4; ++r)
          ((float*)Cout)[(size_t)(rowb + r) * N + col] = v[r];
      } else if (EPI == 4) {
#pragma unroll
        for (int r = 0; r < 4; ++r)
          ((u16*)Cout)[(size_t)(rowb + r) * N + col] = f2bf(v[r]);
      } else {  // EPI == 3
        if (col < 2048) {
          const float sc = (col < 1024) ? QSCALE : 1.0f;
#pragma unroll
          for (int r = 0; r < 4; ++r)
            ((u16*)Cout)[(size_t)(rowb + r) * 2048 + col] = f2bf(v[r] * sc);
        } else {
          const int b = rowb >> 9, s = rowb & 511;
          const int hd = col - 2048;
          ushort4 pk;
          pk.x = f2bf(v[0]); pk.y = f2bf(v[1]); pk.z = f2bf(v[2]); pk.w = f2bf(v[3]);
          *(ushort4*)(vT + ((size_t)(b * NH + (hd >> 6)) * 64 + (hd & 63)) * S_ + s) = pk;
        }
      }
    }
  }
}

// ---------------------------------------------------------------- attention
// R14/R18 kernel, ONLY change: min-blocks 3 -> 4 (LDS 40448*4 = 161792 <= 163840).
// Isolated occupancy experiment: 16 waves/CU vs 12 for a latency-bound kernel.
__global__ __launch_bounds__(256, 4)
void attn_kernel(const u16* __restrict__ qk,
                 const u16* __restrict__ vT,
                 const int* __restrict__ mask,
                 u16* __restrict__ out) {
  __shared__ __align__(16) u16 Qs[32 * 72];
  __shared__ __align__(16) u16 Pl[32 * 520];
  __shared__ __align__(16) float Mlf[512];
  __shared__ __align__(16) float Rsum[32][4];

  const int tid = threadIdx.x;
  const int w = tid >> 6, lane = tid & 63;
  const int bid = blockIdx.x;
  const int widx = (bid & 7) * 512 + (bid >> 3);
  const int qt = widx & 15, h = (widx >> 4) & 15, b = widx >> 8;
  const int q0 = qt * 32;
  const int arow = lane & 15, kg = lane >> 4;

  {
    int r = tid >> 3, slot = tid & 7;
    bf16x8 v = *(const bf16x8*)(qk + (size_t)(b * S_ + q0 + r) * 2048 + h * 64 + slot * 8);
    *(bf16x8*)((char*)Qs + r * 144 + slot * 16) = v;
  }
  Mlf[tid] = (mask[b * S_ + tid] == 0) ? MASKNEG : 0.f;
  Mlf[tid + 256] = (mask[b * S_ + tid + 256] == 0) ? MASKNEG : 0.f;

  const u16* vb = vT + ((size_t)(b * NH + h) * 64 + w * 16 + arow) * S_ + kg * 8;
  bf16x8 vv[8];
#pragma unroll
  for (int i = 0; i < 8; ++i) vv[i] = *(const bf16x8*)(vb + i * 32);

  __syncthreads();

  bf16x8 qf[2][2];
#pragma unroll
  for (int mi = 0; mi < 2; ++mi)
#pragma unroll
    for (int kk = 0; kk < 2; ++kk)
      qf[mi][kk] = *(const bf16x8*)((char*)Qs + (mi * 16 + arow) * 144 + kk * 64 + kg * 16);

  f32x4 s0[8], s1[8];
  const u16* kbase = qk + (size_t)(b * S_) * 2048 + 1024 + h * 64 + kg * 8;
#pragma unroll
  for (int half = 0; half < 2; ++half) {
    bf16x8 kvl[4][2];
#pragma unroll
    for (int j = 0; j < 4; ++j) {
      const int colg = w * 128 + (half * 4 + j) * 16 + arow;
      const u16* kr = kbase + (size_t)colg * 2048;
      kvl[j][0] = *(const bf16x8*)(kr);
      kvl[j][1] = *(const bf16x8*)(kr + 32);
    }
#pragma unroll
    for (int j = 0; j < 4; ++j) {
      const int ni = half * 4 + j;
      f32x4 a0 = {0.f, 0.f, 0.f, 0.f}, a1 = {0.f, 0.f, 0.f, 0.f};
      a0 = __builtin_amdgcn_mfma_f32_16x16x32_bf16(kvl[j][0], qf[0][0], a0, 0, 0, 0);
      a0 = __builtin_amdgcn_mfma_f32_16x16x32_bf16(kvl[j][1], qf[0][1], a0, 0, 0, 0);
      a1 = __builtin_amdgcn_mfma_f32_16x16x32_bf16(kvl[j][0], qf[1][0], a1, 0, 0, 0);
      a1 = __builtin_amdgcn_mfma_f32_16x16x32_bf16(kvl[j][1], qf[1][1], a1, 0, 0, 0);
      const f32x4 mb = *(const f32x4*)&Mlf[w * 128 + ni * 16 + kg * 4];
      s0[ni] = a0 + mb;
      s1[ni] = a1 + mb;
    }
  }

  f32x4 ac0 = {0.f, 0.f, 0.f, 0.f}, ac1 = ac0;
#pragma unroll
  for (int ni = 0; ni < 8; ++ni) {
#pragma unroll
    for (int r = 0; r < 4; ++r) {
      s0[ni][r] = __builtin_amdgcn_exp2f(s0[ni][r]);
      s1[ni][r] = __builtin_amdgcn_exp2f(s1[ni][r]);
    }
    ac0 += s0[ni];
    ac1 += s1[ni];
  }
  float t0 = ac0[0] + ac0[1] + ac0[2] + ac0[3];
  float t1 = ac1[0] + ac1[1] + ac1[2] + ac1[3];
  t0 += __shfl_xor(t0, 16);
  t0 += __shfl_xor(t0, 32);
  t1 += __shfl_xor(t1, 16);
  t1 += __shfl_xor(t1, 32);
  if (kg == 0) {
    Rsum[arow][w] = t0;
    Rsum[16 + arow][w] = t1;
  }

  {
    const int kq = w * 128 + kg * 4;
    char* const p0 = (char*)Pl + (arow * 520 + kq) * 2;
    char* const p1 = (char*)Pl + ((16 + arow) * 520 + kq) * 2;
#pragma unroll
    for (int ni = 0; ni < 8; ++ni) {
      uint2 pk;
      pk.x = cvtpk_bf16(s0[ni][0], s0[ni][1]);
      pk.y = cvtpk_bf16(s0[ni][2], s0[ni][3]);
      *(uint2*)(p0 + ni * 32) = pk;
      pk.x = cvtpk_bf16(s1[ni][0], s1[ni][1]);
      pk.y = cvtpk_bf16(s1[ni][2], s1[ni][3]);
      *(uint2*)(p1 + ni * 32) = pk;
    }
  }
  __syncthreads();

  {
    f32x4 oa[2];
    oa[0] = (f32x4){0.f, 0.f, 0.f, 0.f};
    oa[1] = (f32x4){0.f, 0.f, 0.f, 0.f};
#pragma unroll
    for (int t16 = 0; t16 < 16; ++t16) {
      const int sk0 = t16 * 32;
      bf16x8 bfr = (t16 < 8) ? vv[t16] : *(const bf16x8*)(vb + t16 * 32);
#pragma unroll
      for (int mi = 0; mi < 2; ++mi) {
        bf16x8 pa = *(const bf16x8*)(Pl + (mi * 16 + arow) * 520 + sk0 + kg * 8);
        oa[mi] = __builtin_amdgcn_mfma_f32_16x16x32_bf16(pa, bfr, oa[mi], 0, 0, 0);
      }
    }
#pragma unroll
    for (int mi = 0; mi < 2; ++mi)
#pragma unroll
      for (int r = 0; r < 4; ++r) {
        const int rloc = mi * 16 + kg * 4 + r;
        f32x4 sv = *(const f32x4*)&Rsum[rloc][0];
        const float inv = 1.0f / (sv[0] + sv[1] + sv[2] + sv[3]);
        const int qrow = q0 + rloc;
        out[(size_t)(b * S_ + qrow) * DM + h * 64 + w * 16 + arow] = f2bf(oa[mi][r] * inv);
      }
  }
}

// ---------------------------------------------------------------- residual + LayerNorm
template <int AB, int RB, int WF, int WB>
__global__ __launch_bounds__(256)
void ln_kernel(const void* __restrict__ a, const void* __restrict__ res,
               const float* __restrict__ gamma, const float* __restrict__ beta,
               float* __restrict__ outf, u16* __restrict__ outb) {
  const int row = blockIdx.x, tid = threadIdx.x;
  const int w = tid >> 6, lane = tid & 63;
  const size_t base = (size_t)row * DM + tid * 4;
  float v0, v1, v2, v3;
  {
    float a0, a1, a2, a3, r0, r1, r2, r3;
    if (AB) {
      ushort4 u = *(const ushort4*)((const u16*)a + base);
      a0 = bf2f(u.x); a1 = bf2f(u.y); a2 = bf2f(u.z); a3 = bf2f(u.w);
    } else {
      float4 u = *(const float4*)((const float*)a + base);
      a0 = u.x; a1 = u.y; a2 = u.z; a3 = u.w;
    }
    if (RB) {
      ushort4 u = *(const ushort4*)((const u16*)res + base);
      r0 = bf2f(u.x); r1 = bf2f(u.y); r2 = bf2f(u.z); r3 = bf2f(u.w);
    } else {
      float4 u = *(const float4*)((const float*)res + base);
      r0 = u.x; r1 = u.y; r2 = u.z; r3 = u.w;
    }
    v0 = a0 + r0; v1 = a1 + r1; v2 = a2 + r2; v3 = a3 + r3;
  }
  float s = v0 + v1 + v2 + v3;
  float ss = v0 * v0 + v1 * v1 + v2 * v2 + v3 * v3;
#pragma unroll
  for (int off = 32; off >= 1; off >>= 1) {
    s += __shfl_down(s, off);
    ss += __shfl_down(ss, off);
  }
  __shared__ float ps[4], pss[4], mb[2];
  if (lane == 0) { ps[w] = s; pss[w] = ss; }
  __syncthreads();
  if (tid == 0) {
    float S = ps[0] + ps[1] + ps[2] + ps[3];
    float SS = pss[0] + pss[1] + pss[2] + pss[3];
    float mean = S * (1.0f / DM);
    float var = (SS - (float)DM * mean * mean) * (1.0f / (DM - 1));
    var = fmaxf(var, 0.f);
    mb[0] = mean;
    mb[1] = 1.0f / (sqrtf(var) + 1e-6f);
  }
  __syncthreads();
  const float mean = mb[0], rinv = mb[1];
  const int c = tid * 4;
  float y0 = gamma[c] * (v0 - mean) * rinv + beta[c];
  float y1 = gamma[c + 1] * (v1 - mean) * rinv + beta[c + 1];
  float y2 = gamma[c + 2] * (v2 - mean) * rinv + beta[c + 2];
  float y3 = gamma[c + 3] * (v3 - mean) * rinv + beta[c + 3];
  if (WF) {
    float4 o = {y0, y1, y2, y3};
    *(float4*)(outf + base) = o;
  }
  if (WB) {
    uint2 pk;
    pk.x = (unsigned)f2bf(y0) | ((unsigned)f2bf(y1) << 16);
    pk.y = (unsigned)f2bf(y2) | ((unsigned)f2bf(y3) << 16);
    *(uint2*)(outb + base) = pk;
  }
}

// ---------------------------------------------------------------- launch

extern "C" void kernel_launch(void* const* d_in, const int* in_sizes, int n_in,
                              void* d_out, int out_size, void* d_ws, size_t ws_size,
                              hipStream_t stream) {
  const float* x = (const float*)d_in[0];
  const int* xm = (const int*)d_in[1];
  const float* Wq = (const float*)d_in[2];
  const float* bq = (const float*)d_in[3];
  const float* Wk = (const float*)d_in[4];
  const float* bk = (const float*)d_in[5];
  const float* Wv = (const float*)d_in[6];
  const float* bv = (const float*)d_in[7];
  const float* Wo = (const float*)d_in[8];
  const float* bo = (const float*)d_in[9];
  const float* g1 = (const float*)d_in[10];
  const float* be1 = (const float*)d_in[11];
  const float* W1 = (const float*)d_in[12];
  const float* b1 = (const float*)d_in[13];
  const float* W2 = (const float*)d_in[14];
  const float* b2 = (const float*)d_in[15];
  const float* g2 = (const float*)d_in[16];
  const float* be2 = (const float*)d_in[17];

  char* ws = (char*)d_ws;
  u16* xb = (u16*)(ws);                      // 16,777,216 (stays intact; ln1 residual)
  u16* wqkvt = (u16*)(ws + 16777216);        //  6,291,456
  u16* wot = (u16*)(ws + 23068672);          //  2,097,152
  u16* w1t = (u16*)(ws + 25165824);          //  4,194,304
  u16* w2t = (u16*)(ws + 29360128);          //  4,194,304
  float* bqkv = (float*)(ws + 33554432);     //     12,288
  u16* qkb = (u16*)(ws + 33566720);          // 33,554,432 (reused as ffn1)
  u16* vtb = (u16*)(ws + 67121152);          // 16,777,216
  u16* attnb = (u16*)(ws + 83898368);        // 16,777,216
  u16* attnpb = (u16*)(ws + 100675584);      // 16,777,216 (attn@Wo, bf16)
  u16* f2b = (u16*)(ws + 117452800);         // 16,777,216 (ffn2 out, bf16)
  u16* hb = (u16*)(ws + 134230016);          // 16,777,216 (h bf16)

  prep_all<<<dim3(16396), dim3(256), 0, stream>>>(Wq, Wk, Wv, Wo, W1, W2,
                                                  wqkvt, wot, w1t, w2t,
                                                  bq, bk, bv, bqkv, x, xb);

  // QKV: 256x128 ring-3, 8-wave (grid 768)
  gemm_mfma<3><<<dim3(24, 32), dim3(512), 0, stream>>>(xb, wqkvt, bqkv, (void*)qkb, vtb, 8192, 3072, 1024);
  attn_kernel<<<dim3(4096), dim3(256), 0, stream>>>(qkb, vtb, xm, attnb);
  // attn @ Wo -> bf16  (grid 256)
  gemm_mfma<4><<<dim3(8, 32), dim3(512), 0, stream>>>(attnb, wot, bo, (void*)attnpb, (u16*)nullptr, 8192, 1024, 1024);
  // ln1: bf16 a + bf16 residual (xb) -> bf16 h
  ln_kernel<1, 1, 0, 1><<<dim3(8192), dim3(256), 0, stream>>>(attnpb, xb, g1, be1, (float*)nullptr, hb);
  // FFN1 + GELU -> bf16  (grid 512)
  gemm_mfma<1><<<dim3(16, 32), dim3(512), 0, stream>>>(hb, w1t, b1, (void*)qkb, (u16*)nullptr, 8192, 2048, 1024);
  // FFN2 -> bf16  (grid 256)
  gemm_mfma<4><<<dim3(8, 32), dim3(512), 0, stream>>>(qkb, w2t, b2, (void*)f2b, (u16*)nullptr, 8192, 1024, 2048);
  // ln2: bf16 a + bf16 residual -> fp32 d_out
  ln_kernel<1, 1, 1, 0><<<dim3(8192), dim3(256), 0, stream>>>(f2b, hb, g2, be2, (float*)d_out, (u16*)nullptr);
}

// Round 20
// 285.073 us; speedup vs baseline: 1.0318x; 1.0318x over previous
//
#include <hip/hip_runtime.h>
#include <math.h>

#define B_ 16
#define S_ 512
#define DM 1024
#define NH 16
#define DFF 2048

typedef short bf16x8 __attribute__((ext_vector_type(8)));
typedef float f32x4 __attribute__((ext_vector_type(4)));
typedef unsigned short u16;

__device__ __forceinline__ u16 f2bf(float f) {
  unsigned int u = __float_as_uint(f);
  u += 0x7FFF + ((u >> 16) & 1);
  return (u16)(u >> 16);
}

__device__ __forceinline__ float bf2f(u16 u) {
  return __uint_as_float(((unsigned)u) << 16);
}

__device__ __forceinline__ unsigned cvtpk_bf16(float lo, float hi) {
  unsigned r;
  asm("v_cvt_pk_bf16_f32 %0, %1, %2" : "=v"(r) : "v"(lo), "v"(hi));
  return r;
}

__device__ __forceinline__ float gelu_exact(float x) {
  return 0.5f * x * (1.0f + erff(x * 0.70710678118654752f));
}

__device__ __forceinline__ void gload_lds16(const void* g, void* l) {
  __builtin_amdgcn_global_load_lds((const __attribute__((address_space(1))) void*)g,
                                   (__attribute__((address_space(3))) void*)l, 16, 0, 0);
}

// log2(e)/8: folded into Q at the QKV epilogue so softmax runs in exp2 domain.
#define QSCALE 0.18033688011112042f
#define MASKNEG -1.442695e10f

// ---------------------------------------------------------------- fused preprocessing
__global__ __launch_bounds__(256)
void prep_all(const float* __restrict__ Wq, const float* __restrict__ Wk,
              const float* __restrict__ Wv, const float* __restrict__ Wo,
              const float* __restrict__ W1, const float* __restrict__ W2,
              u16* __restrict__ wqkvt, u16* __restrict__ wot,
              u16* __restrict__ w1t, u16* __restrict__ w2t,
              const float* __restrict__ bq, const float* __restrict__ bk,
              const float* __restrict__ bv, float* __restrict__ bqkv,
              const float* __restrict__ x, u16* __restrict__ xb) {
  const int bid = blockIdx.x;
  if (bid >= 8204) {  // x -> bf16
    int i = ((bid - 8204) * 256 + threadIdx.x) * 4;
    float4 v = *(const float4*)(x + i);
    uint2 pk;
    pk.x = (unsigned)f2bf(v.x) | ((unsigned)f2bf(v.y) << 16);
    pk.y = (unsigned)f2bf(v.z) | ((unsigned)f2bf(v.w) << 16);
    *(uint2*)(xb + i) = pk;
    return;
  }
  if (bid >= 8192) {  // bias concat
    int i = (bid - 8192) * 256 + threadIdx.x;
    bqkv[i] = (i < 1024) ? bq[i] : ((i < 2048) ? bk[i - 1024] : bv[i - 2048]);
    return;
  }
  const float* W;
  u16* Wt;
  int K, N, bx, by;
  if (bid < 4096) {
    const int m = bid >> 10, t = bid & 1023;
    K = 1024; N = 1024; bx = t & 31; by = t >> 5;
    W = (m == 0) ? Wq : (m == 1) ? Wk : (m == 2) ? Wv : Wo;
    Wt = (m == 3) ? wot : wqkvt + m * 1048576;
  } else if (bid < 6144) {
    const int t = bid - 4096;
    K = 1024; N = 2048; bx = t & 63; by = t >> 6; W = W1; Wt = w1t;
  } else {
    const int t = bid - 6144;
    K = 2048; N = 1024; bx = t & 31; by = t >> 5; W = W2; Wt = w2t;
  }
  __shared__ float tile[32][33];
  const int n0 = bx * 32, k0 = by * 32;
  const int tx = threadIdx.x & 31, ty = threadIdx.x >> 5;
#pragma unroll
  for (int j = 0; j < 32; j += 8)
    tile[ty + j][tx] = W[(size_t)(k0 + ty + j) * N + n0 + tx];
  __syncthreads();
#pragma unroll
  for (int j = 0; j < 32; j += 8)
    Wt[(size_t)(n0 + ty + j) * K + k0 + tx] = f2bf(tile[tx][ty + j]);
}

// ---------------------------------------------------------------- GEMM 256x128, BK=32, ring-3, 8-wave
// (R18, verified) one-barrier ring-3; per K-tile {8 ds_read_b128; 3 gload_lds;
// setprio+16 MFMA; vmcnt(3)+lgkmcnt(0); s_barrier}.
// EPI: 1 = GELU -> bf16; 2 = fp32; 3 = QKV split (Q pre-scale + vT 8B-packed); 4 = bf16.
template <int EPI>
__global__ __launch_bounds__(512, 4)
void gemm_mfma(const u16* __restrict__ A, const u16* __restrict__ Bt,
               const float* __restrict__ bias, void* __restrict__ Cout,
               u16* __restrict__ vT, int M, int N, int K) {
  __shared__ __align__(16) char lds[73728];
  const int tid = threadIdx.x;
  const int w = tid >> 6, lane = tid & 63;
  const int wm = w >> 1, wn = w & 1;

  const int gx = gridDim.x;
  const int nwg = gx * gridDim.y;
  const int lin = blockIdx.y * gx + blockIdx.x;
  const int wg = (lin & 7) * (nwg >> 3) + (lin >> 3);
  const int bm = wg / gx, bn = wg % gx;

  const int NT = K >> 5;

  const int srow = tid >> 2;
  const int skel = ((lane & 3) ^ ((lane >> 4) & 3)) * 8;
  const u16* gA = A + (size_t)(bm * 256 + srow) * K + skel;
  const u16* gB = Bt + (size_t)(bn * 128 + srow) * K + skel;
  const size_t rs128 = (size_t)128 * K;
  const int dstb = w * 1024;

  const int lr = lane & 15, kg = lane >> 4;
  const int kslot = (kg ^ ((lr >> 2) & 3)) << 4;
  const int fAoff = (wm * 64 + lr) * 64 + kslot;
  const int fBoff = 16384 + (wn * 64 + lr) * 64 + kslot;

  f32x4 acc[4][4];
#pragma unroll
  for (int i = 0; i < 4; ++i)
#pragma unroll
    for (int j = 0; j < 4; ++j) acc[i][j] = (f32x4){0.f, 0.f, 0.f, 0.f};

#define STAGE_T(t_, sl_)                                         \
  do {                                                           \
    const u16* ga_ = gA + (size_t)(t_) * 32;                     \
    const u16* gb_ = gB + (size_t)(t_) * 32;                     \
    char* d_ = lds + (sl_) * 24576 + dstb;                       \
    gload_lds16(ga_, d_);                                        \
    gload_lds16(ga_ + rs128, d_ + 8192);                         \
    gload_lds16(gb_, d_ + 16384);                                \
  } while (0)

  STAGE_T(0, 0);
  STAGE_T(1, 1);
  asm volatile("s_waitcnt vmcnt(3)" ::: "memory");
  __builtin_amdgcn_s_barrier();
  __builtin_amdgcn_sched_barrier(0);

  int cs = 0, ss = 2;
  for (int t = 0; t < NT; ++t) {
    const int st = (t + 2 < NT) ? (t + 2) : (NT - 1);
    const char* fA = lds + cs * 24576 + fAoff;
    const char* fB = lds + cs * 24576 + fBoff;
    bf16x8 av[4], bv[4];
#pragma unroll
    for (int mi = 0; mi < 4; ++mi) av[mi] = *(const bf16x8*)(fA + mi * 1024);
#pragma unroll
    for (int ni = 0; ni < 4; ++ni) bv[ni] = *(const bf16x8*)(fB + ni * 1024);
    STAGE_T(st, ss);
    __builtin_amdgcn_s_setprio(1);
#pragma unroll
    for (int mi = 0; mi < 4; ++mi)
#pragma unroll
      for (int ni = 0; ni < 4; ++ni)
        acc[mi][ni] = __builtin_amdgcn_mfma_f32_16x16x32_bf16(av[mi], bv[ni], acc[mi][ni], 0, 0, 0);
    __builtin_amdgcn_s_setprio(0);
    asm volatile("s_waitcnt vmcnt(3) lgkmcnt(0)" ::: "memory");
    __builtin_amdgcn_s_barrier();
    __builtin_amdgcn_sched_barrier(0);
    cs = (cs == 2) ? 0 : cs + 1;
    ss = (ss == 2) ? 0 : ss + 1;
  }
#undef STAGE_T

  const int crow0 = bm * 256 + wm * 64;
  const int ccol0 = bn * 128 + wn * 64;
#pragma unroll
  for (int mi = 0; mi < 4; ++mi) {
#pragma unroll
    for (int ni = 0; ni < 4; ++ni) {
      const int col = ccol0 + ni * 16 + lr;
      const float bv_ = bias[col];
      const int rowb = crow0 + mi * 16 + (lane >> 4) * 4;
      float v[4];
#pragma unroll
      for (int r = 0; r < 4; ++r) v[r] = acc[mi][ni][r] + bv_;
      if (EPI == 1) {
#pragma unroll
        for (int r = 0; r < 4; ++r)
          ((u16*)Cout)[(size_t)(rowb + r) * N + col] = f2bf(gelu_exact(v[r]));
      } else if (EPI == 2) {
#pragma unroll
        for (int r = 0; r < 4; ++r)
          ((float*)Cout)[(size_t)(rowb + r) * N + col] = v[r];
      } else if (EPI == 4) {
#pragma unroll
        for (int r = 0; r < 4; ++r)
          ((u16*)Cout)[(size_t)(rowb + r) * N + col] = f2bf(v[r]);
      } else {  // EPI == 3
        if (col < 2048) {
          const float sc = (col < 1024) ? QSCALE : 1.0f;
#pragma unroll
          for (int r = 0; r < 4; ++r)
            ((u16*)Cout)[(size_t)(rowb + r) * 2048 + col] = f2bf(v[r] * sc);
        } else {
          const int b = rowb >> 9, s = rowb & 511;
          const int hd = col - 2048;
          ushort4 pk;
          pk.x = f2bf(v[0]); pk.y = f2bf(v[1]); pk.z = f2bf(v[2]); pk.w = f2bf(v[3]);
          *(ushort4*)(vT + ((size_t)(b * NH + (hd >> 6)) * 64 + (hd & 63)) * S_ + s) = pk;
        }
      }
    }
  }
}

// ---------------------------------------------------------------- attention (R14/R18, verified 72us; 3 blocks/CU)
__global__ __launch_bounds__(256, 3)
void attn_kernel(const u16* __restrict__ qk,
                 const u16* __restrict__ vT,
                 const int* __restrict__ mask,
                 u16* __restrict__ out) {
  __shared__ __align__(16) u16 Qs[32 * 72];
  __shared__ __align__(16) u16 Pl[32 * 520];
  __shared__ __align__(16) float Mlf[512];
  __shared__ __align__(16) float Rsum[32][4];

  const int tid = threadIdx.x;
  const int w = tid >> 6, lane = tid & 63;
  const int bid = blockIdx.x;
  const int widx = (bid & 7) * 512 + (bid >> 3);
  const int qt = widx & 15, h = (widx >> 4) & 15, b = widx >> 8;
  const int q0 = qt * 32;
  const int arow = lane & 15, kg = lane >> 4;

  {
    int r = tid >> 3, slot = tid & 7;
    bf16x8 v = *(const bf16x8*)(qk + (size_t)(b * S_ + q0 + r) * 2048 + h * 64 + slot * 8);
    *(bf16x8*)((char*)Qs + r * 144 + slot * 16) = v;
  }
  Mlf[tid] = (mask[b * S_ + tid] == 0) ? MASKNEG : 0.f;
  Mlf[tid + 256] = (mask[b * S_ + tid + 256] == 0) ? MASKNEG : 0.f;

  const u16* vb = vT + ((size_t)(b * NH + h) * 64 + w * 16 + arow) * S_ + kg * 8;
  bf16x8 vv[8];
#pragma unroll
  for (int i = 0; i < 8; ++i) vv[i] = *(const bf16x8*)(vb + i * 32);

  __syncthreads();

  bf16x8 qf[2][2];
#pragma unroll
  for (int mi = 0; mi < 2; ++mi)
#pragma unroll
    for (int kk = 0; kk < 2; ++kk)
      qf[mi][kk] = *(const bf16x8*)((char*)Qs + (mi * 16 + arow) * 144 + kk * 64 + kg * 16);

  f32x4 s0[8], s1[8];
  const u16* kbase = qk + (size_t)(b * S_) * 2048 + 1024 + h * 64 + kg * 8;
#pragma unroll
  for (int half = 0; half < 2; ++half) {
    bf16x8 kvl[4][2];
#pragma unroll
    for (int j = 0; j < 4; ++j) {
      const int colg = w * 128 + (half * 4 + j) * 16 + arow;
      const u16* kr = kbase + (size_t)colg * 2048;
      kvl[j][0] = *(const bf16x8*)(kr);
      kvl[j][1] = *(const bf16x8*)(kr + 32);
    }
#pragma unroll
    for (int j = 0; j < 4; ++j) {
      const int ni = half * 4 + j;
      f32x4 a0 = {0.f, 0.f, 0.f, 0.f}, a1 = {0.f, 0.f, 0.f, 0.f};
      a0 = __builtin_amdgcn_mfma_f32_16x16x32_bf16(kvl[j][0], qf[0][0], a0, 0, 0, 0);
      a0 = __builtin_amdgcn_mfma_f32_16x16x32_bf16(kvl[j][1], qf[0][1], a0, 0, 0, 0);
      a1 = __builtin_amdgcn_mfma_f32_16x16x32_bf16(kvl[j][0], qf[1][0], a1, 0, 0, 0);
      a1 = __builtin_amdgcn_mfma_f32_16x16x32_bf16(kvl[j][1], qf[1][1], a1, 0, 0, 0);
      const f32x4 mb = *(const f32x4*)&Mlf[w * 128 + ni * 16 + kg * 4];
      s0[ni] = a0 + mb;
      s1[ni] = a1 + mb;
    }
  }

  f32x4 ac0 = {0.f, 0.f, 0.f, 0.f}, ac1 = ac0;
#pragma unroll
  for (int ni = 0; ni < 8; ++ni) {
#pragma unroll
    for (int r = 0; r < 4; ++r) {
      s0[ni][r] = __builtin_amdgcn_exp2f(s0[ni][r]);
      s1[ni][r] = __builtin_amdgcn_exp2f(s1[ni][r]);
    }
    ac0 += s0[ni];
    ac1 += s1[ni];
  }
  float t0 = ac0[0] + ac0[1] + ac0[2] + ac0[3];
  float t1 = ac1[0] + ac1[1] + ac1[2] + ac1[3];
  t0 += __shfl_xor(t0, 16);
  t0 += __shfl_xor(t0, 32);
  t1 += __shfl_xor(t1, 16);
  t1 += __shfl_xor(t1, 32);
  if (kg == 0) {
    Rsum[arow][w] = t0;
    Rsum[16 + arow][w] = t1;
  }

  {
    const int kq = w * 128 + kg * 4;
    char* const p0 = (char*)Pl + (arow * 520 + kq) * 2;
    char* const p1 = (char*)Pl + ((16 + arow) * 520 + kq) * 2;
#pragma unroll
    for (int ni = 0; ni < 8; ++ni) {
      uint2 pk;
      pk.x = cvtpk_bf16(s0[ni][0], s0[ni][1]);
      pk.y = cvtpk_bf16(s0[ni][2], s0[ni][3]);
      *(uint2*)(p0 + ni * 32) = pk;
      pk.x = cvtpk_bf16(s1[ni][0], s1[ni][1]);
      pk.y = cvtpk_bf16(s1[ni][2], s1[ni][3]);
      *(uint2*)(p1 + ni * 32) = pk;
    }
  }
  __syncthreads();

  {
    f32x4 oa[2];
    oa[0] = (f32x4){0.f, 0.f, 0.f, 0.f};
    oa[1] = (f32x4){0.f, 0.f, 0.f, 0.f};
#pragma unroll
    for (int t16 = 0; t16 < 16; ++t16) {
      const int sk0 = t16 * 32;
      bf16x8 bfr = (t16 < 8) ? vv[t16] : *(const bf16x8*)(vb + t16 * 32);
#pragma unroll
      for (int mi = 0; mi < 2; ++mi) {
        bf16x8 pa = *(const bf16x8*)(Pl + (mi * 16 + arow) * 520 + sk0 + kg * 8);
        oa[mi] = __builtin_amdgcn_mfma_f32_16x16x32_bf16(pa, bfr, oa[mi], 0, 0, 0);
      }
    }
#pragma unroll
    for (int mi = 0; mi < 2; ++mi)
#pragma unroll
      for (int r = 0; r < 4; ++r) {
        const int rloc = mi * 16 + kg * 4 + r;
        f32x4 sv = *(const f32x4*)&Rsum[rloc][0];
        const float inv = 1.0f / (sv[0] + sv[1] + sv[2] + sv[3]);
        const int qrow = q0 + rloc;
        out[(size_t)(b * S_ + qrow) * DM + h * 64 + w * 16 + arow] = f2bf(oa[mi][r] * inv);
      }
  }
}

// ---------------------------------------------------------------- residual + LayerNorm
template <int AB, int RB, int WF, int WB>
__global__ __launch_bounds__(256)
void ln_kernel(const void* __restrict__ a, const void* __restrict__ res,
               const float* __restrict__ gamma, const float* __restrict__ beta,
               float* __restrict__ outf, u16* __restrict__ outb) {
  const int row = blockIdx.x, tid = threadIdx.x;
  const int w = tid >> 6, lane = tid & 63;
  const size_t base = (size_t)row * DM + tid * 4;
  float v0, v1, v2, v3;
  {
    float a0, a1, a2, a3, r0, r1, r2, r3;
    if (AB) {
      ushort4 u = *(const ushort4*)((const u16*)a + base);
      a0 = bf2f(u.x); a1 = bf2f(u.y); a2 = bf2f(u.z); a3 = bf2f(u.w);
    } else {
      float4 u = *(const float4*)((const float*)a + base);
      a0 = u.x; a1 = u.y; a2 = u.z; a3 = u.w;
    }
    if (RB) {
      ushort4 u = *(const ushort4*)((const u16*)res + base);
      r0 = bf2f(u.x); r1 = bf2f(u.y); r2 = bf2f(u.z); r3 = bf2f(u.w);
    } else {
      float4 u = *(const float4*)((const float*)res + base);
      r0 = u.x; r1 = u.y; r2 = u.z; r3 = u.w;
    }
    v0 = a0 + r0; v1 = a1 + r1; v2 = a2 + r2; v3 = a3 + r3;
  }
  float s = v0 + v1 + v2 + v3;
  float ss = v0 * v0 + v1 * v1 + v2 * v2 + v3 * v3;
#pragma unroll
  for (int off = 32; off >= 1; off >>= 1) {
    s += __shfl_down(s, off);
    ss += __shfl_down(ss, off);
  }
  __shared__ float ps[4], pss[4], mb[2];
  if (lane == 0) { ps[w] = s; pss[w] = ss; }
  __syncthreads();
  if (tid == 0) {
    float S = ps[0] + ps[1] + ps[2] + ps[3];
    float SS = pss[0] + pss[1] + pss[2] + pss[3];
    float mean = S * (1.0f / DM);
    float var = (SS - (float)DM * mean * mean) * (1.0f / (DM - 1));
    var = fmaxf(var, 0.f);
    mb[0] = mean;
    mb[1] = 1.0f / (sqrtf(var) + 1e-6f);
  }
  __syncthreads();
  const float mean = mb[0], rinv = mb[1];
  const int c = tid * 4;
  float y0 = gamma[c] * (v0 - mean) * rinv + beta[c];
  float y1 = gamma[c + 1] * (v1 - mean) * rinv + beta[c + 1];
  float y2 = gamma[c + 2] * (v2 - mean) * rinv + beta[c + 2];
  float y3 = gamma[c + 3] * (v3 - mean) * rinv + beta[c + 3];
  if (WF) {
    float4 o = {y0, y1, y2, y3};
    *(float4*)(outf + base) = o;
  }
  if (WB) {
    uint2 pk;
    pk.x = (unsigned)f2bf(y0) | ((unsigned)f2bf(y1) << 16);
    pk.y = (unsigned)f2bf(y2) | ((unsigned)f2bf(y3) << 16);
    *(uint2*)(outb + base) = pk;
  }
}

// ---------------------------------------------------------------- launch

extern "C" void kernel_launch(void* const* d_in, const int* in_sizes, int n_in,
                              void* d_out, int out_size, void* d_ws, size_t ws_size,
                              hipStream_t stream) {
  const float* x = (const float*)d_in[0];
  const int* xm = (const int*)d_in[1];
  const float* Wq = (const float*)d_in[2];
  const float* bq = (const float*)d_in[3];
  const float* Wk = (const float*)d_in[4];
  const float* bk = (const float*)d_in[5];
  const float* Wv = (const float*)d_in[6];
  const float* bv = (const float*)d_in[7];
  const float* Wo = (const float*)d_in[8];
  const float* bo = (const float*)d_in[9];
  const float* g1 = (const float*)d_in[10];
  const float* be1 = (const float*)d_in[11];
  const float* W1 = (const float*)d_in[12];
  const float* b1 = (const float*)d_in[13];
  const float* W2 = (const float*)d_in[14];
  const float* b2 = (const float*)d_in[15];
  const float* g2 = (const float*)d_in[16];
  const float* be2 = (const float*)d_in[17];

  char* ws = (char*)d_ws;
  u16* xb = (u16*)(ws);                      // 16,777,216 (stays intact; ln1 residual)
  u16* wqkvt = (u16*)(ws + 16777216);        //  6,291,456
  u16* wot = (u16*)(ws + 23068672);          //  2,097,152
  u16* w1t = (u16*)(ws + 25165824);          //  4,194,304
  u16* w2t = (u16*)(ws + 29360128);          //  4,194,304
  float* bqkv = (float*)(ws + 33554432);     //     12,288
  u16* qkb = (u16*)(ws + 33566720);          // 33,554,432 (reused as ffn1)
  u16* vtb = (u16*)(ws + 67121152);          // 16,777,216
  u16* attnb = (u16*)(ws + 83898368);        // 16,777,216
  u16* attnpb = (u16*)(ws + 100675584);      // 16,777,216 (attn@Wo, bf16)
  u16* f2b = (u16*)(ws + 117452800);         // 16,777,216 (ffn2 out, bf16)
  u16* hb = (u16*)(ws + 134230016);          // 16,777,216 (h bf16)

  prep_all<<<dim3(16396), dim3(256), 0, stream>>>(Wq, Wk, Wv, Wo, W1, W2,
                                                  wqkvt, wot, w1t, w2t,
                                                  bq, bk, bv, bqkv, x, xb);

  // QKV: 256x128 ring-3, 8-wave (grid 768)
  gemm_mfma<3><<<dim3(24, 32), dim3(512), 0, stream>>>(xb, wqkvt, bqkv, (void*)qkb, vtb, 8192, 3072, 1024);
  attn_kernel<<<dim3(4096), dim3(256), 0, stream>>>(qkb, vtb, xm, attnb);
  // attn @ Wo -> bf16  (grid 256)
  gemm_mfma<4><<<dim3(8, 32), dim3(512), 0, stream>>>(attnb, wot, bo, (void*)attnpb, (u16*)nullptr, 8192, 1024, 1024);
  // ln1: bf16 a + bf16 residual (xb) -> bf16 h
  ln_kernel<1, 1, 0, 1><<<dim3(8192), dim3(256), 0, stream>>>(attnpb, xb, g1, be1, (float*)nullptr, hb);
  // FFN1 + GELU -> bf16  (grid 512)
  gemm_mfma<1><<<dim3(16, 32), dim3(512), 0, stream>>>(hb, w1t, b1, (void*)qkb, (u16*)nullptr, 8192, 2048, 1024);
  // FFN2 -> bf16  (grid 256)
  gemm_mfma<4><<<dim3(8, 32), dim3(512), 0, stream>>>(qkb, w2t, b2, (void*)f2b, (u16*)nullptr, 8192, 1024, 2048);
  // ln2: bf16 a + bf16 residual -> fp32 d_out
  ln_kernel<1, 1, 1, 0><<<dim3(8192), dim3(256), 0, stream>>>(f2b, hb, g2, be2, (float*)d_out, (u16*)nullptr);
}